// Round 14
// baseline (376.126 us; speedup 1.0000x reference)
//
#include <hip/hip_runtime.h>
#include <hip/hip_bf16.h>
#include <stdint.h>

#define L_ 2048
#define S_ 2048
#define D_ 64

typedef float f32x4 __attribute__((ext_vector_type(4)));
typedef __bf16 bf16x8 __attribute__((ext_vector_type(8)));

__device__ __forceinline__ unsigned short f2b(float x) {
    return __builtin_bit_cast(unsigned short, (__bf16)x);
}
__device__ __forceinline__ float h2f(unsigned short u) {
    return (float)__builtin_bit_cast(_Float16, u);
}

// ============ fused prep: K->K2, V->V2, bias+mask->mb2 in ONE launch =======
// blocks [0,4096): K fp32 -> K2 bf16 per-(ci,lane) frag order
//   K2 16B units: t = ((((bh*8+it)*8+w)*2+nt)*2+ks)*64 + lan
//   value e = K[bh][s=it*256+w*32+nt*16+li][d=ks*32+g*8+e]
// blocks [4096,8192): V fp32 -> V2 bf16 frag order
//   V2 16B units: t = ((((bh*8+it)*8+w)*4+dt)*64) + lan
//   value e = V[bh][s=it*256+w*32+g*8+e][d=dt*16+li]
// blocks [8192,16384): bias+mask -> mb2 f16 per-(lt16,ci,lane) order
//   mb2 16B units: t = (((b*128+lt)*8+it)*512) + tid512
//   val[nt*4+j] = masked ? -60000 : bias[b][lt*16+g*4+j][it*256+w*32+nt*16+li]
// All three are BW-bound; fusing removes two launch/drain boundaries.
__global__ void prep_all_kernel(const float* __restrict__ k, unsigned short* __restrict__ k2,
                                const float* __restrict__ v, unsigned short* __restrict__ v2,
                                const float* __restrict__ bias, const void* __restrict__ maskp,
                                unsigned short* __restrict__ mb2) {
    const int blk = blockIdx.x;
    if (blk < 4096) {
        const int t = blk * 256 + threadIdx.x;          // 1,048,576 total
        const int lan = t & 63, ks = (t >> 6) & 1, nt = (t >> 7) & 1;
        const int w = (t >> 8) & 7, it = (t >> 11) & 7, bh = t >> 14;
        const int li = lan & 15, g = lan >> 4;
        const int s  = it * 256 + w * 32 + nt * 16 + li;
        const int d0 = ks * 32 + g * 8;
        const float* src = k + ((size_t)bh * S_ + s) * D_ + d0;
        float4 a = *(const float4*)src;
        float4 b = *(const float4*)(src + 4);
        uint4 o;
        o.x = (unsigned)f2b(a.x) | ((unsigned)f2b(a.y) << 16);
        o.y = (unsigned)f2b(a.z) | ((unsigned)f2b(a.w) << 16);
        o.z = (unsigned)f2b(b.x) | ((unsigned)f2b(b.y) << 16);
        o.w = (unsigned)f2b(b.z) | ((unsigned)f2b(b.w) << 16);
        *(uint4*)(k2 + (size_t)t * 8) = o;
    } else if (blk < 8192) {
        const int t = (blk - 4096) * 256 + threadIdx.x; // 1,048,576 total
        const int lan = t & 63, dt = (t >> 6) & 3;
        const int w = (t >> 8) & 7, it = (t >> 11) & 7, bh = t >> 14;
        const int li = lan & 15, g = lan >> 4;
        const int s0 = it * 256 + w * 32 + g * 8;
        const int d  = dt * 16 + li;
        unsigned short o[8];
        #pragma unroll
        for (int e = 0; e < 8; ++e)
            o[e] = f2b(v[((size_t)bh * S_ + s0 + e) * D_ + d]);
        uint4 u;
        u.x = (unsigned)o[0] | ((unsigned)o[1] << 16);
        u.y = (unsigned)o[2] | ((unsigned)o[3] << 16);
        u.z = (unsigned)o[4] | ((unsigned)o[5] << 16);
        u.w = (unsigned)o[6] | ((unsigned)o[7] << 16);
        *(uint4*)(v2 + (size_t)t * 8) = u;
    } else {
        const unsigned* mw = (const unsigned*)maskp;
        int is4 = 1;
        for (int i = 0; i < 64; ++i) {
            unsigned wv = mw[i];
            if (!(wv == 0u || wv == 1u || wv == 0x3F800000u)) { is4 = 0; break; }
        }
        const int t = (blk - 8192) * 256 + threadIdx.x; // 2,097,152 total
        const int tid = t & 511, it = (t >> 9) & 7, lt = (t >> 12) & 127, b = t >> 19;
        const int w = tid >> 6, lan = tid & 63, g = lan >> 4, li = lan & 15;
        const unsigned short NEG = __builtin_bit_cast(unsigned short, (_Float16)(-60000.0f));
        const int* maski = (const int*)maskp;
        const unsigned char* maskb = (const unsigned char*)maskp;
        unsigned short o[8];
        #pragma unroll
        for (int nt = 0; nt < 2; ++nt)
          #pragma unroll
          for (int j = 0; j < 4; ++j) {
              size_t idx = ((size_t)b * L_ + lt * 16 + g * 4 + j) * S_
                         + it * 256 + w * 32 + nt * 16 + li;
              int m = is4 ? (maski[idx] != 0) : (maskb[idx] != 0);
              o[nt * 4 + j] = m ? NEG
                                : __builtin_bit_cast(unsigned short, (_Float16)bias[idx]);
          }
        uint4 u;
        u.x = (unsigned)o[0] | ((unsigned)o[1] << 16);
        u.y = (unsigned)o[2] | ((unsigned)o[3] << 16);
        u.z = (unsigned)o[4] | ((unsigned)o[5] << 16);
        u.w = (unsigned)o[6] | ((unsigned)o[7] << 16);
        *(uint4*)(mb2 + (size_t)t * 8) = u;
    }
}

// ============ main fused attention: R13 + depth-2 pass-1 prefetch ==========
// R13 structure (1024 blocks x 4 autonomous waves, 32 rows/wave via shared-K
// rg pair, 2-pass defer-max, zero barriers, setprio on MFMA clusters,
// __launch_bounds__(256,3)) -- best measured (354.2). ONE change, pass 1
// only: unroll-2 A/B rotating prefetch with issue-after-consume. Per-XCD
// working set (K/V 4MB + mb2 stream 4.2MB) > 4MB L2, so both pass-1 streams
// partially miss to L3 (~600-900cy); depth-1 prefetch covers only ~1 iter
// (~450cy). The A/B scheme re-issues a buffer's registers for ci+2 right
// after its MFMAs consume it -> ~2 iterations (~1000cy) of cover at ZERO
// extra registers (pass-2 peak dominates the allocator anyway). Pass 2
// byte-identical to R13. Identical loads + math order -> absmax unchanged.
__launch_bounds__(256, 3)
__global__ void attn_main_kernel(const float* __restrict__ q,
                                 const unsigned short* __restrict__ mb2,
                                 const unsigned short* __restrict__ k2,
                                 const unsigned short* __restrict__ v2,
                                 float* __restrict__ outp,
                                 float* __restrict__ attnp)
{
    __shared__ __align__(16) char lds[10240];    // 4 waves x 2 rg x 1280 B
    const int tid = threadIdx.x;
    const int w = tid >> 6, lan = tid & 63, g = lan >> 4, li = lan & 15;

    // bijective XCD chunking (1024 % 8 == 0): XCD x gets 128 consecutive c.
    // c = ((b*16+h)*16 + stripe): per XCD = 8 consecutive (b,h) x 16 stripes
    // -> 8 heads' K2/V2 (4.2 MB) L2-hot; mb2 streams from L3.
    const int c      = ((blockIdx.x & 7) << 7) | (blockIdx.x >> 3);
    const int b      = c >> 8;
    const int h      = (c >> 4) & 15;
    const int stripe = c & 15;
    const int bh     = (b << 4) | h;
    const int l0w    = stripe * 128 + w * 32;    // this wave's 32-row base
    const int lt0    = stripe * 8 + w * 2;       // 16-row slice index (+rg)

    const unsigned short* mbb0 = mb2 + (size_t)(b * 128 + lt0) * 32768 + (size_t)lan * 8;
    const unsigned short* mbb1 = mbb0 + 32768;
    const unsigned short* kb   = k2 + (size_t)bh * 131072 + (size_t)lan * 8;
    const unsigned short* vb   = v2 + (size_t)bh * 131072 + (size_t)lan * 8;
    char* pb0 = lds + (w * 2 + 0) * 1280;        // per-(wave,rg) P bounce
    char* pb1 = lds + (w * 2 + 1) * 1280;
    const f32x4 vzero = {0.f, 0.f, 0.f, 0.f};

    // ---- Q fragments: rg x ks, held in regs across both passes ----
    bf16x8 qf[2][2];
    #pragma unroll
    for (int rg = 0; rg < 2; ++rg)
      #pragma unroll
      for (int ks = 0; ks < 2; ++ks) {
        const float* qp = q + ((size_t)bh * L_ + (l0w + rg * 16 + li)) * D_ + ks * 32 + g * 8;
        float4 xv = *(const float4*)qp;
        float4 yv = *(const float4*)(qp + 4);
        bf16x8 f;
        f[0]=(__bf16)xv.x; f[1]=(__bf16)xv.y; f[2]=(__bf16)xv.z; f[3]=(__bf16)xv.w;
        f[4]=(__bf16)yv.x; f[5]=(__bf16)yv.y; f[6]=(__bf16)yv.z; f[7]=(__bf16)yv.w;
        qf[rg][ks] = f;
    }

    // ========== pass 1: row sums; A/B depth-2 rotating prefetch ==========
    float vs[2][4] = {{0.f,0.f,0.f,0.f},{0.f,0.f,0.f,0.f}};
    uint4 kA[4], kB[4];
    uint4 mpA0, mpA1, mpB0, mpB1;
    #pragma unroll
    for (int ff = 0; ff < 4; ++ff) {
        kA[ff] = *(const uint4*)(kb + ff * 512);          // ci=0
        kB[ff] = *(const uint4*)(kb + 2048 + ff * 512);   // ci=1
    }
    mpA0 = *(const uint4*)(mbb0);
    mpA1 = *(const uint4*)(mbb1);
    mpB0 = *(const uint4*)(mbb0 + 512);
    mpB1 = *(const uint4*)(mbb1 + 512);
    #pragma unroll 1
    for (int ci = 0; ci < 64; ci += 2) {
        // ---- even half: consume A(ci); refill A <- ci+2 after consume ----
        {
            const int cn = (ci + 2 < 64) ? ci + 2 : 62;   // harmless re-load
            f32x4 a00 = vzero, a01 = vzero, a10 = vzero, a11 = vzero;
            __builtin_amdgcn_s_setprio(1);
            a00 = __builtin_amdgcn_mfma_f32_16x16x32_bf16(
                qf[0][0], __builtin_bit_cast(bf16x8, kA[0]), a00, 0, 0, 0);
            a00 = __builtin_amdgcn_mfma_f32_16x16x32_bf16(
                qf[0][1], __builtin_bit_cast(bf16x8, kA[1]), a00, 0, 0, 0);
            a01 = __builtin_amdgcn_mfma_f32_16x16x32_bf16(
                qf[0][0], __builtin_bit_cast(bf16x8, kA[2]), a01, 0, 0, 0);
            a01 = __builtin_amdgcn_mfma_f32_16x16x32_bf16(
                qf[0][1], __builtin_bit_cast(bf16x8, kA[3]), a01, 0, 0, 0);
            a10 = __builtin_amdgcn_mfma_f32_16x16x32_bf16(
                qf[1][0], __builtin_bit_cast(bf16x8, kA[0]), a10, 0, 0, 0);
            a10 = __builtin_amdgcn_mfma_f32_16x16x32_bf16(
                qf[1][1], __builtin_bit_cast(bf16x8, kA[1]), a10, 0, 0, 0);
            a11 = __builtin_amdgcn_mfma_f32_16x16x32_bf16(
                qf[1][0], __builtin_bit_cast(bf16x8, kA[2]), a11, 0, 0, 0);
            a11 = __builtin_amdgcn_mfma_f32_16x16x32_bf16(
                qf[1][1], __builtin_bit_cast(bf16x8, kA[3]), a11, 0, 0, 0);
            __builtin_amdgcn_s_setprio(0);
            // A consumed -> re-issue A as the ci+2 load (depth-2 cover)
            #pragma unroll
            for (int ff = 0; ff < 4; ++ff)
                kA[ff] = *(const uint4*)(kb + cn * 2048 + ff * 512);
            float mbv0[2][4], mbv1[2][4];
            mbv0[0][0] = h2f((unsigned short)(mpA0.x & 0xffff));
            mbv0[0][1] = h2f((unsigned short)(mpA0.x >> 16));
            mbv0[0][2] = h2f((unsigned short)(mpA0.y & 0xffff));
            mbv0[0][3] = h2f((unsigned short)(mpA0.y >> 16));
            mbv0[1][0] = h2f((unsigned short)(mpA0.z & 0xffff));
            mbv0[1][1] = h2f((unsigned short)(mpA0.z >> 16));
            mbv0[1][2] = h2f((unsigned short)(mpA0.w & 0xffff));
            mbv0[1][3] = h2f((unsigned short)(mpA0.w >> 16));
            mbv1[0][0] = h2f((unsigned short)(mpA1.x & 0xffff));
            mbv1[0][1] = h2f((unsigned short)(mpA1.x >> 16));
            mbv1[0][2] = h2f((unsigned short)(mpA1.y & 0xffff));
            mbv1[0][3] = h2f((unsigned short)(mpA1.y >> 16));
            mbv1[1][0] = h2f((unsigned short)(mpA1.z & 0xffff));
            mbv1[1][1] = h2f((unsigned short)(mpA1.z >> 16));
            mbv1[1][2] = h2f((unsigned short)(mpA1.w & 0xffff));
            mbv1[1][3] = h2f((unsigned short)(mpA1.w >> 16));
            #pragma unroll
            for (int j = 0; j < 4; ++j) {
                vs[0][j] += __expf(fmaf(a00[j], 0.125f, mbv0[0][j]))
                          + __expf(fmaf(a01[j], 0.125f, mbv0[1][j]));
                vs[1][j] += __expf(fmaf(a10[j], 0.125f, mbv1[0][j]))
                          + __expf(fmaf(a11[j], 0.125f, mbv1[1][j]));
            }
            mpA0 = *(const uint4*)(mbb0 + cn * 512);
            mpA1 = *(const uint4*)(mbb1 + cn * 512);
        }
        // ---- odd half: consume B(ci+1); refill B <- ci+3 after consume ----
        {
            const int cn = (ci + 3 < 64) ? ci + 3 : 63;   // harmless re-load
            f32x4 a00 = vzero, a01 = vzero, a10 = vzero, a11 = vzero;
            __builtin_amdgcn_s_setprio(1);
            a00 = __builtin_amdgcn_mfma_f32_16x16x32_bf16(
                qf[0][0], __builtin_bit_cast(bf16x8, kB[0]), a00, 0, 0, 0);
            a00 = __builtin_amdgcn_mfma_f32_16x16x32_bf16(
                qf[0][1], __builtin_bit_cast(bf16x8, kB[1]), a00, 0, 0, 0);
            a01 = __builtin_amdgcn_mfma_f32_16x16x32_bf16(
                qf[0][0], __builtin_bit_cast(bf16x8, kB[2]), a01, 0, 0, 0);
            a01 = __builtin_amdgcn_mfma_f32_16x16x32_bf16(
                qf[0][1], __builtin_bit_cast(bf16x8, kB[3]), a01, 0, 0, 0);
            a10 = __builtin_amdgcn_mfma_f32_16x16x32_bf16(
                qf[1][0], __builtin_bit_cast(bf16x8, kB[0]), a10, 0, 0, 0);
            a10 = __builtin_amdgcn_mfma_f32_16x16x32_bf16(
                qf[1][1], __builtin_bit_cast(bf16x8, kB[1]), a10, 0, 0, 0);
            a11 = __builtin_amdgcn_mfma_f32_16x16x32_bf16(
                qf[1][0], __builtin_bit_cast(bf16x8, kB[2]), a11, 0, 0, 0);
            a11 = __builtin_amdgcn_mfma_f32_16x16x32_bf16(
                qf[1][1], __builtin_bit_cast(bf16x8, kB[3]), a11, 0, 0, 0);
            __builtin_amdgcn_s_setprio(0);
            #pragma unroll
            for (int ff = 0; ff < 4; ++ff)
                kB[ff] = *(const uint4*)(kb + cn * 2048 + ff * 512);
            float mbv0[2][4], mbv1[2][4];
            mbv0[0][0] = h2f((unsigned short)(mpB0.x & 0xffff));
            mbv0[0][1] = h2f((unsigned short)(mpB0.x >> 16));
            mbv0[0][2] = h2f((unsigned short)(mpB0.y & 0xffff));
            mbv0[0][3] = h2f((unsigned short)(mpB0.y >> 16));
            mbv0[1][0] = h2f((unsigned short)(mpB0.z & 0xffff));
            mbv0[1][1] = h2f((unsigned short)(mpB0.z >> 16));
            mbv0[1][2] = h2f((unsigned short)(mpB0.w & 0xffff));
            mbv0[1][3] = h2f((unsigned short)(mpB0.w >> 16));
            mbv1[0][0] = h2f((unsigned short)(mpB1.x & 0xffff));
            mbv1[0][1] = h2f((unsigned short)(mpB1.x >> 16));
            mbv1[0][2] = h2f((unsigned short)(mpB1.y & 0xffff));
            mbv1[0][3] = h2f((unsigned short)(mpB1.y >> 16));
            mbv1[1][0] = h2f((unsigned short)(mpB1.z & 0xffff));
            mbv1[1][1] = h2f((unsigned short)(mpB1.z >> 16));
            mbv1[1][2] = h2f((unsigned short)(mpB1.w & 0xffff));
            mbv1[1][3] = h2f((unsigned short)(mpB1.w >> 16));
            #pragma unroll
            for (int j = 0; j < 4; ++j) {
                vs[0][j] += __expf(fmaf(a00[j], 0.125f, mbv0[0][j]))
                          + __expf(fmaf(a01[j], 0.125f, mbv0[1][j]));
                vs[1][j] += __expf(fmaf(a10[j], 0.125f, mbv1[0][j]))
                          + __expf(fmaf(a11[j], 0.125f, mbv1[1][j]));
            }
            mpB0 = *(const uint4*)(mbb0 + cn * 512);
            mpB1 = *(const uint4*)(mbb1 + cn * 512);
        }
    }
    // wave-local reduce over 16 li lanes -> 1/sum (no barrier, no LDS)
    float rinv[2][4];
    #pragma unroll
    for (int rg = 0; rg < 2; ++rg)
      #pragma unroll
      for (int j = 0; j < 4; ++j) {
        float s = vs[rg][j];
        s += __shfl_xor(s, 1);
        s += __shfl_xor(s, 2);
        s += __shfl_xor(s, 4);
        s += __shfl_xor(s, 8);
        rinv[rg][j] = 1.0f / s;
    }

    // ====== pass 2: recompute s, normalize, store attn, PV (no barriers) ===
    f32x4 oacc[2][4];
    #pragma unroll
    for (int rg = 0; rg < 2; ++rg)
      #pragma unroll
      for (int dt = 0; dt < 4; ++dt) oacc[rg][dt] = vzero;
    float* attnw = attnp + (size_t)bh * ((size_t)L_ * S_) + (size_t)l0w * S_;

    uint4 kf[4], kn[4];
    #pragma unroll
    for (int ff = 0; ff < 4; ++ff) kf[ff] = *(const uint4*)(kb + ff * 512);
    uint4 mp0 = *(const uint4*)(mbb0);
    uint4 mp1 = *(const uint4*)(mbb1);
    #pragma unroll 1
    for (int ci = 0; ci < 64; ++ci) {
        const int cn = (ci < 63) ? ci + 1 : 63;
        #pragma unroll
        for (int ff = 0; ff < 4; ++ff)
            kn[ff] = *(const uint4*)(kb + cn * 2048 + ff * 512);
        uint4 mp0n = *(const uint4*)(mbb0 + cn * 512);
        uint4 mp1n = *(const uint4*)(mbb1 + cn * 512);
        uint4 vf[4];
        #pragma unroll
        for (int dt = 0; dt < 4; ++dt)
            vf[dt] = *(const uint4*)(vb + ci * 2048 + dt * 512);
        #pragma unroll
        for (int rg = 0; rg < 2; ++rg) {
            const uint4 mp = rg ? mp1 : mp0;
            char* pbuf = rg ? pb1 : pb0;
            f32x4 a0 = vzero, a1 = vzero;
            __builtin_amdgcn_s_setprio(1);
            a0 = __builtin_amdgcn_mfma_f32_16x16x32_bf16(
                qf[rg][0], __builtin_bit_cast(bf16x8, kf[0]), a0, 0, 0, 0);
            a0 = __builtin_amdgcn_mfma_f32_16x16x32_bf16(
                qf[rg][1], __builtin_bit_cast(bf16x8, kf[1]), a0, 0, 0, 0);
            a1 = __builtin_amdgcn_mfma_f32_16x16x32_bf16(
                qf[rg][0], __builtin_bit_cast(bf16x8, kf[2]), a1, 0, 0, 0);
            a1 = __builtin_amdgcn_mfma_f32_16x16x32_bf16(
                qf[rg][1], __builtin_bit_cast(bf16x8, kf[3]), a1, 0, 0, 0);
            __builtin_amdgcn_s_setprio(0);
            float mbv[2][4];
            mbv[0][0] = h2f((unsigned short)(mp.x & 0xffff));
            mbv[0][1] = h2f((unsigned short)(mp.x >> 16));
            mbv[0][2] = h2f((unsigned short)(mp.y & 0xffff));
            mbv[0][3] = h2f((unsigned short)(mp.y >> 16));
            mbv[1][0] = h2f((unsigned short)(mp.z & 0xffff));
            mbv[1][1] = h2f((unsigned short)(mp.z >> 16));
            mbv[1][2] = h2f((unsigned short)(mp.w & 0xffff));
            mbv[1][3] = h2f((unsigned short)(mp.w >> 16));
            float a[2][4];
            #pragma unroll
            for (int j = 0; j < 4; ++j) {
                a[0][j] = __expf(fmaf(a0[j], 0.125f, mbv[0][j])) * rinv[rg][j];
                a[1][j] = __expf(fmaf(a1[j], 0.125f, mbv[1][j])) * rinv[rg][j];
            }
            // nontemporal attn stores; j-outer/nt-inner pairs 128B lines
            float* aw = attnw + (size_t)(rg * 16) * S_;
            #pragma unroll
            for (int j = 0; j < 4; ++j)
              #pragma unroll
              for (int nt = 0; nt < 2; ++nt)
                  __builtin_nontemporal_store(a[nt][j],
                      aw + (size_t)(g * 4 + j) * S_ + ci * 32 + nt * 16 + li);
            // P -> per-(wave,rg) LDS transpose bounce (same-wave lgkmcnt
            // ordering, no barrier)
            #pragma unroll
            for (int nt = 0; nt < 2; ++nt)
              #pragma unroll
              for (int j = 0; j < 4; ++j)
                  *(unsigned short*)(pbuf + (g * 4 + j) * 80 + (nt * 16 + li) * 2)
                      = f2b(a[nt][j]);
            bf16x8 pf = *(const bf16x8*)(pbuf + li * 80 + g * 16);
            __builtin_amdgcn_s_setprio(1);
            #pragma unroll
            for (int dt = 0; dt < 4; ++dt)
                oacc[rg][dt] = __builtin_amdgcn_mfma_f32_16x16x32_bf16(
                    pf, __builtin_bit_cast(bf16x8, vf[dt]), oacc[rg][dt], 0, 0, 0);
            __builtin_amdgcn_s_setprio(0);
        }
        #pragma unroll
        for (int ff = 0; ff < 4; ++ff) kf[ff] = kn[ff];
        mp0 = mp0n; mp1 = mp1n;
    }

    // ================= out stores (wave-local, no reduction) ===============
    #pragma unroll
    for (int rg = 0; rg < 2; ++rg) {
        float* outw = outp + ((size_t)bh * L_ + (l0w + rg * 16)) * D_;
        #pragma unroll
        for (int dt = 0; dt < 4; ++dt)
          #pragma unroll
          for (int j = 0; j < 4; ++j)
              __builtin_nontemporal_store(oacc[rg][dt][j],
                  outw + (size_t)(g * 4 + j) * D_ + dt * 16 + li);
    }
}

extern "C" void kernel_launch(void* const* d_in, const int* in_sizes, int n_in,
                              void* d_out, int out_size, void* d_ws, size_t ws_size,
                              hipStream_t stream) {
    const float* q    = (const float*)d_in[0];
    const float* k    = (const float*)d_in[1];
    const float* v    = (const float*)d_in[2];
    const void*  mask = d_in[3];
    const float* bias = (const float*)d_in[4];

    unsigned short* k2  = (unsigned short*)d_ws;                  // 16.78 MB
    unsigned short* v2  = k2 + (size_t)8388608;                   // 16.78 MB
    unsigned short* mb2 = k2 + (size_t)16777216;                  // 33.55 MB

    float* outp  = (float*)d_out;                                 // [B,H,L,D]
    float* attnp = outp + (size_t)8388608;                        // [B,H,L,S]

    prep_all_kernel<<<16384, 256, 0, stream>>>(k, k2, v, v2, bias, mask, mb2);
    attn_main_kernel<<<1024, 256, 0, stream>>>(q, mb2, k2, v2, outp, attnp);
}

// Round 15
// 353.611 us; speedup vs baseline: 1.0637x; 1.0637x over previous
//
#include <hip/hip_runtime.h>
#include <hip/hip_bf16.h>
#include <stdint.h>

#define L_ 2048
#define S_ 2048
#define D_ 64

typedef float f32x4 __attribute__((ext_vector_type(4)));
typedef __bf16 bf16x8 __attribute__((ext_vector_type(8)));

__device__ __forceinline__ unsigned short f2b(float x) {
    return __builtin_bit_cast(unsigned short, (__bf16)x);
}
__device__ __forceinline__ float h2f(unsigned short u) {
    return (float)__builtin_bit_cast(_Float16, u);
}

// ============ fused prep: K->K2, V->V2, bias+mask->mb2 in ONE launch =======
// blocks [0,4096): K fp32 -> K2 bf16 per-(ci,lane) frag order
//   K2 16B units: t = ((((bh*8+it)*8+w)*2+nt)*2+ks)*64 + lan
//   value e = K[bh][s=it*256+w*32+nt*16+li][d=ks*32+g*8+e]
// blocks [4096,8192): V fp32 -> V2 bf16 frag order
//   V2 16B units: t = ((((bh*8+it)*8+w)*4+dt)*64) + lan
//   value e = V[bh][s=it*256+w*32+g*8+e][d=dt*16+li]
// blocks [8192,16384): bias+mask -> mb2 f16 per-(lt16,ci,lane) order
//   mb2 16B units: t = (((b*128+lt)*8+it)*512) + tid512
//   val[nt*4+j] = masked ? -60000 : bias[b][lt*16+g*4+j][it*256+w*32+nt*16+li]
// All three are BW-bound; fusing removes two launch/drain boundaries.
__global__ void prep_all_kernel(const float* __restrict__ k, unsigned short* __restrict__ k2,
                                const float* __restrict__ v, unsigned short* __restrict__ v2,
                                const float* __restrict__ bias, const void* __restrict__ maskp,
                                unsigned short* __restrict__ mb2) {
    const int blk = blockIdx.x;
    if (blk < 4096) {
        const int t = blk * 256 + threadIdx.x;          // 1,048,576 total
        const int lan = t & 63, ks = (t >> 6) & 1, nt = (t >> 7) & 1;
        const int w = (t >> 8) & 7, it = (t >> 11) & 7, bh = t >> 14;
        const int li = lan & 15, g = lan >> 4;
        const int s  = it * 256 + w * 32 + nt * 16 + li;
        const int d0 = ks * 32 + g * 8;
        const float* src = k + ((size_t)bh * S_ + s) * D_ + d0;
        float4 a = *(const float4*)src;
        float4 b = *(const float4*)(src + 4);
        uint4 o;
        o.x = (unsigned)f2b(a.x) | ((unsigned)f2b(a.y) << 16);
        o.y = (unsigned)f2b(a.z) | ((unsigned)f2b(a.w) << 16);
        o.z = (unsigned)f2b(b.x) | ((unsigned)f2b(b.y) << 16);
        o.w = (unsigned)f2b(b.z) | ((unsigned)f2b(b.w) << 16);
        *(uint4*)(k2 + (size_t)t * 8) = o;
    } else if (blk < 8192) {
        const int t = (blk - 4096) * 256 + threadIdx.x; // 1,048,576 total
        const int lan = t & 63, dt = (t >> 6) & 3;
        const int w = (t >> 8) & 7, it = (t >> 11) & 7, bh = t >> 14;
        const int li = lan & 15, g = lan >> 4;
        const int s0 = it * 256 + w * 32 + g * 8;
        const int d  = dt * 16 + li;
        unsigned short o[8];
        #pragma unroll
        for (int e = 0; e < 8; ++e)
            o[e] = f2b(v[((size_t)bh * S_ + s0 + e) * D_ + d]);
        uint4 u;
        u.x = (unsigned)o[0] | ((unsigned)o[1] << 16);
        u.y = (unsigned)o[2] | ((unsigned)o[3] << 16);
        u.z = (unsigned)o[4] | ((unsigned)o[5] << 16);
        u.w = (unsigned)o[6] | ((unsigned)o[7] << 16);
        *(uint4*)(v2 + (size_t)t * 8) = u;
    } else {
        const unsigned* mw = (const unsigned*)maskp;
        int is4 = 1;
        for (int i = 0; i < 64; ++i) {
            unsigned wv = mw[i];
            if (!(wv == 0u || wv == 1u || wv == 0x3F800000u)) { is4 = 0; break; }
        }
        const int t = (blk - 8192) * 256 + threadIdx.x; // 2,097,152 total
        const int tid = t & 511, it = (t >> 9) & 7, lt = (t >> 12) & 127, b = t >> 19;
        const int w = tid >> 6, lan = tid & 63, g = lan >> 4, li = lan & 15;
        const unsigned short NEG = __builtin_bit_cast(unsigned short, (_Float16)(-60000.0f));
        const int* maski = (const int*)maskp;
        const unsigned char* maskb = (const unsigned char*)maskp;
        unsigned short o[8];
        #pragma unroll
        for (int nt = 0; nt < 2; ++nt)
          #pragma unroll
          for (int j = 0; j < 4; ++j) {
              size_t idx = ((size_t)b * L_ + lt * 16 + g * 4 + j) * S_
                         + it * 256 + w * 32 + nt * 16 + li;
              int m = is4 ? (maski[idx] != 0) : (maskb[idx] != 0);
              o[nt * 4 + j] = m ? NEG
                                : __builtin_bit_cast(unsigned short, (_Float16)bias[idx]);
          }
        uint4 u;
        u.x = (unsigned)o[0] | ((unsigned)o[1] << 16);
        u.y = (unsigned)o[2] | ((unsigned)o[3] << 16);
        u.z = (unsigned)o[4] | ((unsigned)o[5] << 16);
        u.w = (unsigned)o[6] | ((unsigned)o[7] << 16);
        *(uint4*)(mb2 + (size_t)t * 8) = u;
    }
}

// ============ main fused attention: fat waves, zero barriers (R13 exact) ===
// Verified best (354.2 us): 1024 blocks x 4 autonomous waves, 32 rows/wave
// via shared-K rg pair, 2-pass defer-max softmax (C=0), K+mb2 register
// double-buffer at depth 1 issued at loop-top, setprio(1) around MFMA
// clusters, zero barriers, __launch_bounds__(256,3).
// Refuted alternatives (evidence): 4-blk/CU residency (R9 404 spill, R10
// 439 thin-tile read-amp, R11 410 SGPR-surgery), LDS staging + counted
// vmcnt (R6/R7 ~445), depth-2 issue-after-consume prefetch (R14 376 --
// hand-pinning load order defeats hipcc scheduling). Traffic at planned
// minimum: FETCH ~0.36 GB, WRITE ~1.15 GB (attn f32 is 1.07 GB mandatory).
__launch_bounds__(256, 3)
__global__ void attn_main_kernel(const float* __restrict__ q,
                                 const unsigned short* __restrict__ mb2,
                                 const unsigned short* __restrict__ k2,
                                 const unsigned short* __restrict__ v2,
                                 float* __restrict__ outp,
                                 float* __restrict__ attnp)
{
    __shared__ __align__(16) char lds[10240];    // 4 waves x 2 rg x 1280 B
    const int tid = threadIdx.x;
    const int w = tid >> 6, lan = tid & 63, g = lan >> 4, li = lan & 15;

    // bijective XCD chunking (1024 % 8 == 0): XCD x gets 128 consecutive c.
    // c = ((b*16+h)*16 + stripe): per XCD = 8 consecutive (b,h) x 16 stripes
    // -> 8 heads' K2/V2 (4.2 MB) L2-hot; mb2 streams from L3.
    const int c      = ((blockIdx.x & 7) << 7) | (blockIdx.x >> 3);
    const int b      = c >> 8;
    const int h      = (c >> 4) & 15;
    const int stripe = c & 15;
    const int bh     = (b << 4) | h;
    const int l0w    = stripe * 128 + w * 32;    // this wave's 32-row base
    const int lt0    = stripe * 8 + w * 2;       // 16-row slice index (+rg)

    const unsigned short* mbb0 = mb2 + (size_t)(b * 128 + lt0) * 32768 + (size_t)lan * 8;
    const unsigned short* mbb1 = mbb0 + 32768;
    const unsigned short* kb   = k2 + (size_t)bh * 131072 + (size_t)lan * 8;
    const unsigned short* vb   = v2 + (size_t)bh * 131072 + (size_t)lan * 8;
    char* pb0 = lds + (w * 2 + 0) * 1280;        // per-(wave,rg) P bounce
    char* pb1 = lds + (w * 2 + 1) * 1280;
    const f32x4 vzero = {0.f, 0.f, 0.f, 0.f};

    // ---- Q fragments: rg x ks, held in regs across both passes ----
    bf16x8 qf[2][2];
    #pragma unroll
    for (int rg = 0; rg < 2; ++rg)
      #pragma unroll
      for (int ks = 0; ks < 2; ++ks) {
        const float* qp = q + ((size_t)bh * L_ + (l0w + rg * 16 + li)) * D_ + ks * 32 + g * 8;
        float4 xv = *(const float4*)qp;
        float4 yv = *(const float4*)(qp + 4);
        bf16x8 f;
        f[0]=(__bf16)xv.x; f[1]=(__bf16)xv.y; f[2]=(__bf16)xv.z; f[3]=(__bf16)xv.w;
        f[4]=(__bf16)yv.x; f[5]=(__bf16)yv.y; f[6]=(__bf16)yv.z; f[7]=(__bf16)yv.w;
        qf[rg][ks] = f;
    }

    // ================= pass 1: row sums (registers only) =================
    float vs[2][4] = {{0.f,0.f,0.f,0.f},{0.f,0.f,0.f,0.f}};
    uint4 kf[4], kn[4];
    #pragma unroll
    for (int ff = 0; ff < 4; ++ff) kf[ff] = *(const uint4*)(kb + ff * 512);
    uint4 mp0 = *(const uint4*)(mbb0);
    uint4 mp1 = *(const uint4*)(mbb1);
    #pragma unroll 1
    for (int ci = 0; ci < 64; ++ci) {
        const int cn = (ci < 63) ? ci + 1 : 63;  // harmless re-load on last
        #pragma unroll
        for (int ff = 0; ff < 4; ++ff)
            kn[ff] = *(const uint4*)(kb + cn * 2048 + ff * 512);
        uint4 mp0n = *(const uint4*)(mbb0 + cn * 512);
        uint4 mp1n = *(const uint4*)(mbb1 + cn * 512);
        #pragma unroll
        for (int rg = 0; rg < 2; ++rg) {
            const uint4 mp = rg ? mp1 : mp0;
            f32x4 a0 = vzero, a1 = vzero;
            __builtin_amdgcn_s_setprio(1);
            a0 = __builtin_amdgcn_mfma_f32_16x16x32_bf16(
                qf[rg][0], __builtin_bit_cast(bf16x8, kf[0]), a0, 0, 0, 0);
            a0 = __builtin_amdgcn_mfma_f32_16x16x32_bf16(
                qf[rg][1], __builtin_bit_cast(bf16x8, kf[1]), a0, 0, 0, 0);
            a1 = __builtin_amdgcn_mfma_f32_16x16x32_bf16(
                qf[rg][0], __builtin_bit_cast(bf16x8, kf[2]), a1, 0, 0, 0);
            a1 = __builtin_amdgcn_mfma_f32_16x16x32_bf16(
                qf[rg][1], __builtin_bit_cast(bf16x8, kf[3]), a1, 0, 0, 0);
            __builtin_amdgcn_s_setprio(0);
            float mbv[2][4];
            mbv[0][0] = h2f((unsigned short)(mp.x & 0xffff));
            mbv[0][1] = h2f((unsigned short)(mp.x >> 16));
            mbv[0][2] = h2f((unsigned short)(mp.y & 0xffff));
            mbv[0][3] = h2f((unsigned short)(mp.y >> 16));
            mbv[1][0] = h2f((unsigned short)(mp.z & 0xffff));
            mbv[1][1] = h2f((unsigned short)(mp.z >> 16));
            mbv[1][2] = h2f((unsigned short)(mp.w & 0xffff));
            mbv[1][3] = h2f((unsigned short)(mp.w >> 16));
            #pragma unroll
            for (int j = 0; j < 4; ++j) {
                float e0 = __expf(fmaf(a0[j], 0.125f, mbv[0][j]));
                float e1 = __expf(fmaf(a1[j], 0.125f, mbv[1][j]));
                vs[rg][j] += e0 + e1;
            }
        }
        #pragma unroll
        for (int ff = 0; ff < 4; ++ff) kf[ff] = kn[ff];
        mp0 = mp0n; mp1 = mp1n;
    }
    // wave-local reduce over 16 li lanes -> 1/sum (no barrier, no LDS)
    float rinv[2][4];
    #pragma unroll
    for (int rg = 0; rg < 2; ++rg)
      #pragma unroll
      for (int j = 0; j < 4; ++j) {
        float s = vs[rg][j];
        s += __shfl_xor(s, 1);
        s += __shfl_xor(s, 2);
        s += __shfl_xor(s, 4);
        s += __shfl_xor(s, 8);
        rinv[rg][j] = 1.0f / s;
    }

    // ====== pass 2: recompute s, normalize, store attn, PV (no barriers) ===
    f32x4 oacc[2][4];
    #pragma unroll
    for (int rg = 0; rg < 2; ++rg)
      #pragma unroll
      for (int dt = 0; dt < 4; ++dt) oacc[rg][dt] = vzero;
    float* attnw = attnp + (size_t)bh * ((size_t)L_ * S_) + (size_t)l0w * S_;

    #pragma unroll
    for (int ff = 0; ff < 4; ++ff) kf[ff] = *(const uint4*)(kb + ff * 512);
    mp0 = *(const uint4*)(mbb0);
    mp1 = *(const uint4*)(mbb1);
    #pragma unroll 1
    for (int ci = 0; ci < 64; ++ci) {
        const int cn = (ci < 63) ? ci + 1 : 63;
        #pragma unroll
        for (int ff = 0; ff < 4; ++ff)
            kn[ff] = *(const uint4*)(kb + cn * 2048 + ff * 512);
        uint4 mp0n = *(const uint4*)(mbb0 + cn * 512);
        uint4 mp1n = *(const uint4*)(mbb1 + cn * 512);
        uint4 vf[4];
        #pragma unroll
        for (int dt = 0; dt < 4; ++dt)
            vf[dt] = *(const uint4*)(vb + ci * 2048 + dt * 512);
        #pragma unroll
        for (int rg = 0; rg < 2; ++rg) {
            const uint4 mp = rg ? mp1 : mp0;
            char* pbuf = rg ? pb1 : pb0;
            f32x4 a0 = vzero, a1 = vzero;
            __builtin_amdgcn_s_setprio(1);
            a0 = __builtin_amdgcn_mfma_f32_16x16x32_bf16(
                qf[rg][0], __builtin_bit_cast(bf16x8, kf[0]), a0, 0, 0, 0);
            a0 = __builtin_amdgcn_mfma_f32_16x16x32_bf16(
                qf[rg][1], __builtin_bit_cast(bf16x8, kf[1]), a0, 0, 0, 0);
            a1 = __builtin_amdgcn_mfma_f32_16x16x32_bf16(
                qf[rg][0], __builtin_bit_cast(bf16x8, kf[2]), a1, 0, 0, 0);
            a1 = __builtin_amdgcn_mfma_f32_16x16x32_bf16(
                qf[rg][1], __builtin_bit_cast(bf16x8, kf[3]), a1, 0, 0, 0);
            __builtin_amdgcn_s_setprio(0);
            float mbv[2][4];
            mbv[0][0] = h2f((unsigned short)(mp.x & 0xffff));
            mbv[0][1] = h2f((unsigned short)(mp.x >> 16));
            mbv[0][2] = h2f((unsigned short)(mp.y & 0xffff));
            mbv[0][3] = h2f((unsigned short)(mp.y >> 16));
            mbv[1][0] = h2f((unsigned short)(mp.z & 0xffff));
            mbv[1][1] = h2f((unsigned short)(mp.z >> 16));
            mbv[1][2] = h2f((unsigned short)(mp.w & 0xffff));
            mbv[1][3] = h2f((unsigned short)(mp.w >> 16));
            float a[2][4];
            #pragma unroll
            for (int j = 0; j < 4; ++j) {
                a[0][j] = __expf(fmaf(a0[j], 0.125f, mbv[0][j])) * rinv[rg][j];
                a[1][j] = __expf(fmaf(a1[j], 0.125f, mbv[1][j])) * rinv[rg][j];
            }
            // nontemporal attn stores; j-outer/nt-inner pairs 128B lines
            float* aw = attnw + (size_t)(rg * 16) * S_;
            #pragma unroll
            for (int j = 0; j < 4; ++j)
              #pragma unroll
              for (int nt = 0; nt < 2; ++nt)
                  __builtin_nontemporal_store(a[nt][j],
                      aw + (size_t)(g * 4 + j) * S_ + ci * 32 + nt * 16 + li);
            // P -> per-(wave,rg) LDS transpose bounce (same-wave lgkmcnt
            // ordering, no barrier)
            #pragma unroll
            for (int nt = 0; nt < 2; ++nt)
              #pragma unroll
              for (int j = 0; j < 4; ++j)
                  *(unsigned short*)(pbuf + (g * 4 + j) * 80 + (nt * 16 + li) * 2)
                      = f2b(a[nt][j]);
            bf16x8 pf = *(const bf16x8*)(pbuf + li * 80 + g * 16);
            __builtin_amdgcn_s_setprio(1);
            #pragma unroll
            for (int dt = 0; dt < 4; ++dt)
                oacc[rg][dt] = __builtin_amdgcn_mfma_f32_16x16x32_bf16(
                    pf, __builtin_bit_cast(bf16x8, vf[dt]), oacc[rg][dt], 0, 0, 0);
            __builtin_amdgcn_s_setprio(0);
        }
        #pragma unroll
        for (int ff = 0; ff < 4; ++ff) kf[ff] = kn[ff];
        mp0 = mp0n; mp1 = mp1n;
    }

    // ================= out stores (wave-local, no reduction) ===============
    #pragma unroll
    for (int rg = 0; rg < 2; ++rg) {
        float* outw = outp + ((size_t)bh * L_ + (l0w + rg * 16)) * D_;
        #pragma unroll
        for (int dt = 0; dt < 4; ++dt)
          #pragma unroll
          for (int j = 0; j < 4; ++j)
              __builtin_nontemporal_store(oacc[rg][dt][j],
                  outw + (size_t)(g * 4 + j) * D_ + dt * 16 + li);
    }
}

extern "C" void kernel_launch(void* const* d_in, const int* in_sizes, int n_in,
                              void* d_out, int out_size, void* d_ws, size_t ws_size,
                              hipStream_t stream) {
    const float* q    = (const float*)d_in[0];
    const float* k    = (const float*)d_in[1];
    const float* v    = (const float*)d_in[2];
    const void*  mask = d_in[3];
    const float* bias = (const float*)d_in[4];

    unsigned short* k2  = (unsigned short*)d_ws;                  // 16.78 MB
    unsigned short* v2  = k2 + (size_t)8388608;                   // 16.78 MB
    unsigned short* mb2 = k2 + (size_t)16777216;                  // 33.55 MB

    float* outp  = (float*)d_out;                                 // [B,H,L,D]
    float* attnp = outp + (size_t)8388608;                        // [B,H,L,S]

    prep_all_kernel<<<16384, 256, 0, stream>>>(k, k2, v, v2, bias, mask, mb2);
    attn_main_kernel<<<1024, 256, 0, stream>>>(q, mb2, k2, v2, outp, attnp);
}